// Round 2
// baseline (2957.789 us; speedup 1.0000x reference)
//
#include <hip/hip_runtime.h>
#include <math.h>

#define HW 4096
#define NN 32

// ---------------------------------------------------------------------------
// Kernel T: transpose x[n][c][pos] -> xT[n][g][pos][c16]  (channel-last, so a
// gathered sample position's 16 channels are one 64B line = 4 float4 loads).
// grid 2048 = 32n*4g*16chunk ; block 256. LDS tile pad 17 -> conflict-free.
// ---------------------------------------------------------------------------
__global__ __launch_bounds__(256) void transpose_x(const float* __restrict__ x,
                                                   float* __restrict__ xT)
{
    __shared__ float tile[256 * 17];
    int bx = blockIdx.x;
    int n = bx >> 6, g = (bx >> 4) & 3, chunk = bx & 15;
    int t = threadIdx.x;
    const float* xb = x + (size_t)(n * 64 + g * 16) * HW + chunk * 256;

    #pragma unroll
    for (int r = 0; r < 16; r++) {
        int idx = r * 256 + t;          // 16 channels x 256 pos
        int c = idx >> 8, p = idx & 255;
        tile[p * 17 + c] = xb[c * HW + p];   // read coalesced; write stride 17
    }
    __syncthreads();

    float* ob = xT + ((size_t)(n * 4 + g) * HW + chunk * 256) * 16;
    #pragma unroll
    for (int r = 0; r < 4; r++) {
        int idx = r * 256 + t;          // 1024 float4 stores, coalesced
        int p = idx >> 2, q = idx & 3;
        float4 v;
        v.x = tile[p * 17 + q * 4 + 0];
        v.y = tile[p * 17 + q * 4 + 1];
        v.z = tile[p * 17 + q * 4 + 2];
        v.w = tile[p * 17 + q * 4 + 3];
        ((float4*)ob)[idx] = v;
    }
}

// ---------------------------------------------------------------------------
// Kernel B: fused offset-conv + deformable gather + 16x16x9 contraction.
// grid 2048 = 32n*4g*16chunk ; block 256 (one spatial pos / thread).
// All x reads come from xT as float4 (16 channels per 4 loads).
// ---------------------------------------------------------------------------
__global__ __launch_bounds__(256) void fused_deform(const float* __restrict__ xT,
                                                    const float* __restrict__ w_off,
                                                    const float* __restrict__ b_off,
                                                    const float* __restrict__ w_dc,
                                                    const float* __restrict__ b_dc,
                                                    float* __restrict__ outpre)
{
    __shared__ float wo[2592];   // [c*9+ij][18] broadcast over lanes
    __shared__ float wd[2304];   // [c*9+k][16]
    int bx = blockIdx.x;
    int n = bx >> 6, g = (bx >> 4) & 3, chunk = bx & 15;
    int t = threadIdx.x;

    for (int idx = t; idx < 2592; idx += 256) {
        int cij = idx / 18, d = idx - cij * 18;
        wo[idx] = w_off[(g * 18 + d) * 144 + cij];
    }
    for (int idx = t; idx < 2304; idx += 256) {
        int ck = idx >> 4, o = idx & 15;
        wd[idx] = w_dc[(g * 16 + o) * 144 + ck];
    }
    __syncthreads();

    int pos = chunk * 256 + t;
    int h = pos >> 6, w = pos & 63;
    const float4* xb = (const float4*)xT + (size_t)(n * 4 + g) * HW * 4;

    // ---- Phase 1: 3x3 grouped conv -> 18 offsets in registers ----
    float off[18];
    #pragma unroll
    for (int d = 0; d < 18; d++) off[d] = b_off[g * 18 + d];

    #pragma unroll
    for (int i = 0; i < 3; i++) {
        int hh = h - 1 + i;
        #pragma unroll
        for (int j = 0; j < 3; j++) {
            int ww = w - 1 + j;
            bool valid = (hh >= 0) && (hh < 64) && (ww >= 0) && (ww < 64);
            int idx = valid ? (hh * 64 + ww) : 0;
            float4 v0 = xb[idx * 4 + 0];
            float4 v1 = xb[idx * 4 + 1];
            float4 v2 = xb[idx * 4 + 2];
            float4 v3 = xb[idx * 4 + 3];
            if (!valid) {
                v0 = make_float4(0.f, 0.f, 0.f, 0.f); v1 = v0; v2 = v0; v3 = v0;
            }
            float xv[16];
            *(float4*)&xv[0]  = v0; *(float4*)&xv[4]  = v1;
            *(float4*)&xv[8]  = v2; *(float4*)&xv[12] = v3;
            #pragma unroll
            for (int c = 0; c < 16; c++) {
                const float* wp = &wo[(c * 9 + i * 3 + j) * 18];
                #pragma unroll
                for (int d = 0; d < 18; d++) off[d] = fmaf(wp[d], xv[c], off[d]);
            }
        }
    }

    // ---- Phase 2: bilinear gather + contraction ----
    float acc[16];
    #pragma unroll
    for (int o = 0; o < 16; o++) acc[o] = b_dc[g * 16 + o];

    #pragma unroll
    for (int k = 0; k < 9; k++) {
        float py = (float)(h - 1 + k / 3) + off[2 * k + 0];
        float px = (float)(w - 1 + k % 3) + off[2 * k + 1];
        float y0f = floorf(py), x0f = floorf(px);
        float ly = py - y0f, lx = px - x0f;
        int y0 = (int)y0f, x0 = (int)x0f;
        int y1 = y0 + 1,  x1 = x0 + 1;
        float vy0 = (y0 >= 0 && y0 < 64) ? 1.f : 0.f;
        float vy1 = (y1 >= 0 && y1 < 64) ? 1.f : 0.f;
        float vx0 = (x0 >= 0 && x0 < 64) ? 1.f : 0.f;
        float vx1 = (x1 >= 0 && x1 < 64) ? 1.f : 0.f;
        float w00 = (1.f - ly) * (1.f - lx) * vy0 * vx0;
        float w01 = (1.f - ly) * lx         * vy0 * vx1;
        float w10 = ly         * (1.f - lx) * vy1 * vx0;
        float w11 = ly         * lx         * vy1 * vx1;
        int yc0 = min(max(y0, 0), 63) * 64, yc1 = min(max(y1, 0), 63) * 64;
        int xc0 = min(max(x0, 0), 63),      xc1 = min(max(x1, 0), 63);
        int i00 = yc0 + xc0, i01 = yc0 + xc1, i10 = yc1 + xc0, i11 = yc1 + xc1;

        #pragma unroll
        for (int q = 0; q < 4; q++) {
            float4 a = xb[i00 * 4 + q];
            float4 b = xb[i01 * 4 + q];
            float4 c = xb[i10 * 4 + q];
            float4 d = xb[i11 * 4 + q];
            float4 val;
            val.x = w00 * a.x + w01 * b.x + w10 * c.x + w11 * d.x;
            val.y = w00 * a.y + w01 * b.y + w10 * c.y + w11 * d.y;
            val.z = w00 * a.z + w01 * b.z + w10 * c.z + w11 * d.z;
            val.w = w00 * a.w + w01 * b.w + w10 * c.w + w11 * d.w;
            const float* wp0 = &wd[((q * 4 + 0) * 9 + k) * 16];
            const float* wp1 = &wd[((q * 4 + 1) * 9 + k) * 16];
            const float* wp2 = &wd[((q * 4 + 2) * 9 + k) * 16];
            const float* wp3 = &wd[((q * 4 + 3) * 9 + k) * 16];
            #pragma unroll
            for (int o = 0; o < 16; o++) {
                acc[o] = fmaf(wp0[o], val.x, acc[o]);
                acc[o] = fmaf(wp1[o], val.y, acc[o]);
                acc[o] = fmaf(wp2[o], val.z, acc[o]);
                acc[o] = fmaf(wp3[o], val.w, acc[o]);
            }
        }
    }

    float* op = outpre + (size_t)(n * 64 + g * 16) * HW + pos;
    #pragma unroll
    for (int o = 0; o < 16; o++) op[o * HW] = acc[o];
}

// ---------------------------------------------------------------------------
// Kernel C: per-(n,cout) spatial mean/var + exact GELU + transposed store.
// ---------------------------------------------------------------------------
__global__ __launch_bounds__(256) void norm_gelu(const float* __restrict__ outpre,
                                                 float* __restrict__ out)
{
    __shared__ float red[8];
    int bx = blockIdx.x;
    int n  = bx >> 6;
    int co = bx & 63;
    int t  = threadIdx.x;

    const float4* base = (const float4*)(outpre + (size_t)(n * 64 + co) * HW);
    float4 v[4];
    float s = 0.f;
    #pragma unroll
    for (int r = 0; r < 4; r++) {
        v[r] = base[t + r * 256];
        s += v[r].x + v[r].y + v[r].z + v[r].w;
    }
    #pragma unroll
    for (int o2 = 32; o2 > 0; o2 >>= 1) s += __shfl_down(s, o2, 64);
    int wid = t >> 6, lane = t & 63;
    if (lane == 0) red[wid] = s;
    __syncthreads();
    float mean = (red[0] + red[1] + red[2] + red[3]) * (1.f / 4096.f);

    float sq = 0.f;
    #pragma unroll
    for (int r = 0; r < 4; r++) {
        float a = v[r].x - mean, b = v[r].y - mean;
        float c = v[r].z - mean, d = v[r].w - mean;
        sq += a * a + b * b + c * c + d * d;
    }
    #pragma unroll
    for (int o2 = 32; o2 > 0; o2 >>= 1) sq += __shfl_down(sq, o2, 64);
    if (lane == 0) red[4 + wid] = sq;
    __syncthreads();
    float var  = (red[4] + red[5] + red[6] + red[7]) * (1.f / 4096.f);
    float rstd = rsqrtf(var + 1e-5f);

    int b = n >> 3, d = n & 7;
    float4* outp = (float4*)(out + ((size_t)(b * 64 + co) * 8 + d) * HW);
    #pragma unroll
    for (int r = 0; r < 4; r++) {
        float xs[4] = {v[r].x, v[r].y, v[r].z, v[r].w};
        float4 res;
        float* rp = (float*)&res;
        #pragma unroll
        for (int q = 0; q < 4; q++) {
            float xn = (xs[q] - mean) * rstd;
            rp[q] = 0.5f * xn * (1.f + erff(xn * 0.70710678118654752f));
        }
        outp[t + r * 256] = res;
    }
}

// ---------------------------------------------------------------------------
extern "C" void kernel_launch(void* const* d_in, const int* in_sizes, int n_in,
                              void* d_out, int out_size, void* d_ws, size_t ws_size,
                              hipStream_t stream) {
    const float* x     = (const float*)d_in[0];
    const float* w_off = (const float*)d_in[1];
    const float* b_off = (const float*)d_in[2];
    const float* w_dc  = (const float*)d_in[3];
    const float* b_dc  = (const float*)d_in[4];
    float* out = (float*)d_out;

    float* xT     = (float*)d_ws;                     // 32*4*4096*16 = 32 MB
    float* outpre = xT + (size_t)NN * 4 * HW * 16;    // 32*64*4096   = 32 MB

    transpose_x <<<2048, 256, 0, stream>>>(x, xT);
    fused_deform<<<2048, 256, 0, stream>>>(xT, w_off, b_off, w_dc, b_dc, outpre);
    norm_gelu   <<<2048, 256, 0, stream>>>(outpre, out);
}

// Round 3
// 252.078 us; speedup vs baseline: 11.7336x; 11.7336x over previous
//
#include <hip/hip_runtime.h>
#include <hip/hip_bf16.h>
#include <math.h>

#define HW 4096
#define NN 32

__device__ inline unsigned short bfbits(float a) {
    __hip_bfloat16 h = __float2bfloat16(a);
    unsigned short u;
    __builtin_memcpy(&u, &h, 2);
    return u;
}
__device__ inline unsigned packbf(float a, float b) {
    return (unsigned)bfbits(a) | ((unsigned)bfbits(b) << 16);
}
__device__ inline float bflo(unsigned u) { return __uint_as_float(u << 16); }
__device__ inline float bfhi(unsigned u) { return __uint_as_float(u & 0xffff0000u); }

// ---------------------------------------------------------------------------
// Kernel T: x[n][c][pos] (fp32) -> xT[n][g][pos][c16] (bf16, 32B per pos).
// grid 2048 = 32n*4g*16chunk ; block 256.
// ---------------------------------------------------------------------------
__global__ __launch_bounds__(256) void transpose_x(const float* __restrict__ x,
                                                   unsigned short* __restrict__ xT)
{
    __shared__ float tile[256 * 17];
    int bx = blockIdx.x;
    int n = bx >> 6, g = (bx >> 4) & 3, chunk = bx & 15;
    int t = threadIdx.x;
    const float* xb = x + (size_t)(n * 64 + g * 16) * HW + chunk * 256;

    #pragma unroll
    for (int r = 0; r < 16; r++) {
        int idx = r * 256 + t;
        int c = idx >> 8, p = idx & 255;
        tile[p * 17 + c] = xb[c * HW + p];   // coalesced read; stride-17 write
    }
    __syncthreads();

    uint4* ob = (uint4*)(xT + ((size_t)(n * 4 + g) * HW + chunk * 256) * 16);
    #pragma unroll
    for (int r = 0; r < 2; r++) {
        int idx = r * 256 + t;               // 512 uint4 stores, coalesced
        int p = idx >> 1, half = idx & 1;
        const float* tp = &tile[p * 17 + half * 8];
        uint4 v;
        v.x = packbf(tp[0], tp[1]);
        v.y = packbf(tp[2], tp[3]);
        v.z = packbf(tp[4], tp[5]);
        v.w = packbf(tp[6], tp[7]);
        ob[idx] = v;
    }
}

// ---------------------------------------------------------------------------
// Kernel A: grouped 3x3 offset conv (round-1 structure, bf16 output).
// grid 2048 = 32n*4g*16rowchunk ; block 256 = 4 rows x 64 cols.
// ---------------------------------------------------------------------------
__global__ __launch_bounds__(256) void off_conv(const float* __restrict__ x,
                                                const float* __restrict__ w_off,
                                                const float* __restrict__ b_off,
                                                __hip_bfloat16* __restrict__ off)
{
    __shared__ float wl[2592];   // [c*9+ij][18]
    __shared__ float bl[18];
    int bx = blockIdx.x;
    int n  = bx >> 6;
    int g  = (bx >> 4) & 3;
    int rc = bx & 15;
    int t  = threadIdx.x;

    for (int idx = t; idx < 2592; idx += 256) {
        int cij = idx / 18, d = idx - cij * 18;
        wl[idx] = w_off[(g * 18 + d) * 144 + cij];
    }
    if (t < 18) bl[t] = b_off[g * 18 + t];
    __syncthreads();

    int h = rc * 4 + (t >> 6);
    int w = t & 63;
    const float* xb = x + (size_t)(n * 64 + g * 16) * HW;

    float acc[18];
    #pragma unroll
    for (int d = 0; d < 18; d++) acc[d] = bl[d];

    #pragma unroll 1
    for (int c = 0; c < 16; c++) {
        const float* xc = xb + c * HW;
        #pragma unroll
        for (int i = 0; i < 3; i++) {
            int hh = h - 1 + i;
            bool vy = (hh >= 0) && (hh < 64);
            #pragma unroll
            for (int j = 0; j < 3; j++) {
                int ww = w - 1 + j;
                bool vx = (ww >= 0) && (ww < 64);
                float xv = (vy && vx) ? xc[hh * 64 + ww] : 0.f;
                const float* wp = &wl[(c * 9 + i * 3 + j) * 18];
                #pragma unroll
                for (int d = 0; d < 18; d++) acc[d] = fmaf(wp[d], xv, acc[d]);
            }
        }
    }

    int pos = h * 64 + w;
    __hip_bfloat16* ob = off + (size_t)(n * 72 + g * 18) * HW + pos;
    #pragma unroll
    for (int d = 0; d < 18; d++) ob[d * HW] = __float2bfloat16(acc[d]);
}

// ---------------------------------------------------------------------------
// Kernel B: deformable bilinear gather (bf16 uint4, 2 pos/thread) + 16x16x9.
// grid 1024 = 32n*4g*8chunk ; block 256 ; thread owns pos0=chunk*512+t, pos1=pos0+256.
// ---------------------------------------------------------------------------
__device__ inline void bilin_setup(int h, int w, int ki, int kj, float dy, float dx,
                                   float* ww, int* ss) {
    float py = (float)(h - 1 + ki) + dy;
    float px = (float)(w - 1 + kj) + dx;
    float y0f = floorf(py), x0f = floorf(px);
    float ly = py - y0f, lx = px - x0f;
    int y0 = (int)y0f, x0 = (int)x0f;
    int y1 = y0 + 1, x1 = x0 + 1;
    float vy0 = (y0 >= 0 && y0 < 64) ? 1.f : 0.f;
    float vy1 = (y1 >= 0 && y1 < 64) ? 1.f : 0.f;
    float vx0 = (x0 >= 0 && x0 < 64) ? 1.f : 0.f;
    float vx1 = (x1 >= 0 && x1 < 64) ? 1.f : 0.f;
    ww[0] = (1.f - ly) * (1.f - lx) * vy0 * vx0;
    ww[1] = (1.f - ly) * lx         * vy0 * vx1;
    ww[2] = ly         * (1.f - lx) * vy1 * vx0;
    ww[3] = ly         * lx         * vy1 * vx1;
    int yc0 = min(max(y0, 0), 63) * 64, yc1 = min(max(y1, 0), 63) * 64;
    int xc0 = min(max(x0, 0), 63),      xc1 = min(max(x1, 0), 63);
    ss[0] = yc0 + xc0; ss[1] = yc0 + xc1; ss[2] = yc1 + xc0; ss[3] = yc1 + xc1;
}

__device__ inline void bilin8(uint4 A, uint4 B, uint4 C, uint4 D,
                              const float* ww, float* val) {
    const unsigned* ua = (const unsigned*)&A;
    const unsigned* ub = (const unsigned*)&B;
    const unsigned* uc = (const unsigned*)&C;
    const unsigned* ud = (const unsigned*)&D;
    #pragma unroll
    for (int j = 0; j < 4; j++) {
        val[2*j]   = ww[0]*bflo(ua[j]) + ww[1]*bflo(ub[j]) + ww[2]*bflo(uc[j]) + ww[3]*bflo(ud[j]);
        val[2*j+1] = ww[0]*bfhi(ua[j]) + ww[1]*bfhi(ub[j]) + ww[2]*bfhi(uc[j]) + ww[3]*bfhi(ud[j]);
    }
}

__global__ __launch_bounds__(256) void deform_conv(const unsigned short* __restrict__ xT,
                                                   const __hip_bfloat16* __restrict__ off,
                                                   const float* __restrict__ w_dc,
                                                   const float* __restrict__ b_dc,
                                                   float* __restrict__ outpre)
{
    __shared__ float wl[2304];   // [(c*9+k)*16 + o]
    int bx = blockIdx.x;
    int n = bx >> 5, g = (bx >> 3) & 3, chunk = bx & 7;
    int t = threadIdx.x;

    for (int idx = t; idx < 2304; idx += 256) {
        int ck = idx >> 4, o = idx & 15;
        wl[idx] = w_dc[(g * 16 + o) * 144 + ck];
    }
    __syncthreads();

    int pos0 = chunk * 512 + t;
    int pos1 = pos0 + 256;
    int h0 = pos0 >> 6, w0 = pos0 & 63;
    int h1 = pos1 >> 6, w1 = pos1 & 63;
    const uint4* xb = (const uint4*)xT + (size_t)(n * 4 + g) * HW * 2;
    const __hip_bfloat16* ob = off + (size_t)(n * 72 + g * 18) * HW;

    float acc0[16], acc1[16];
    #pragma unroll
    for (int o = 0; o < 16; o++) { float b = b_dc[g * 16 + o]; acc0[o] = b; acc1[o] = b; }

    #pragma unroll 1
    for (int k = 0; k < 9; k++) {
        int ki = k / 3, kj = k - ki * 3;
        float dy0 = __bfloat162float(ob[(2 * k + 0) * HW + pos0]);
        float dx0 = __bfloat162float(ob[(2 * k + 1) * HW + pos0]);
        float dy1 = __bfloat162float(ob[(2 * k + 0) * HW + pos1]);
        float dx1 = __bfloat162float(ob[(2 * k + 1) * HW + pos1]);
        float ww0[4], ww1[4];
        int ss0[4], ss1[4];
        bilin_setup(h0, w0, ki, kj, dy0, dx0, ww0, ss0);
        bilin_setup(h1, w1, ki, kj, dy1, dx1, ww1, ss1);

        #pragma unroll
        for (int q = 0; q < 2; q++) {
            float val0[8], val1[8];
            bilin8(xb[ss0[0] * 2 + q], xb[ss0[1] * 2 + q],
                   xb[ss0[2] * 2 + q], xb[ss0[3] * 2 + q], ww0, val0);
            bilin8(xb[ss1[0] * 2 + q], xb[ss1[1] * 2 + q],
                   xb[ss1[2] * 2 + q], xb[ss1[3] * 2 + q], ww1, val1);
            #pragma unroll
            for (int c = 0; c < 8; c++) {
                const float4* wp = (const float4*)&wl[((q * 8 + c) * 9 + k) * 16];
                float v0 = val0[c], v1 = val1[c];
                #pragma unroll
                for (int o4 = 0; o4 < 4; o4++) {
                    float4 wv = wp[o4];
                    acc0[o4*4+0] = fmaf(wv.x, v0, acc0[o4*4+0]);
                    acc0[o4*4+1] = fmaf(wv.y, v0, acc0[o4*4+1]);
                    acc0[o4*4+2] = fmaf(wv.z, v0, acc0[o4*4+2]);
                    acc0[o4*4+3] = fmaf(wv.w, v0, acc0[o4*4+3]);
                    acc1[o4*4+0] = fmaf(wv.x, v1, acc1[o4*4+0]);
                    acc1[o4*4+1] = fmaf(wv.y, v1, acc1[o4*4+1]);
                    acc1[o4*4+2] = fmaf(wv.z, v1, acc1[o4*4+2]);
                    acc1[o4*4+3] = fmaf(wv.w, v1, acc1[o4*4+3]);
                }
            }
        }
    }

    float* op = outpre + (size_t)(n * 64 + g * 16) * HW;
    #pragma unroll
    for (int o = 0; o < 16; o++) {
        op[o * HW + pos0] = acc0[o];
        op[o * HW + pos1] = acc1[o];
    }
}

// ---------------------------------------------------------------------------
// Kernel C: per-(n,cout) spatial mean/var + exact GELU + transposed store.
// ---------------------------------------------------------------------------
__global__ __launch_bounds__(256) void norm_gelu(const float* __restrict__ outpre,
                                                 float* __restrict__ out)
{
    __shared__ float red[8];
    int bx = blockIdx.x;
    int n  = bx >> 6;
    int co = bx & 63;
    int t  = threadIdx.x;

    const float4* base = (const float4*)(outpre + (size_t)(n * 64 + co) * HW);
    float4 v[4];
    float s = 0.f;
    #pragma unroll
    for (int r = 0; r < 4; r++) {
        v[r] = base[t + r * 256];
        s += v[r].x + v[r].y + v[r].z + v[r].w;
    }
    #pragma unroll
    for (int o2 = 32; o2 > 0; o2 >>= 1) s += __shfl_down(s, o2, 64);
    int wid = t >> 6, lane = t & 63;
    if (lane == 0) red[wid] = s;
    __syncthreads();
    float mean = (red[0] + red[1] + red[2] + red[3]) * (1.f / 4096.f);

    float sq = 0.f;
    #pragma unroll
    for (int r = 0; r < 4; r++) {
        float a = v[r].x - mean, b = v[r].y - mean;
        float c = v[r].z - mean, d = v[r].w - mean;
        sq += a * a + b * b + c * c + d * d;
    }
    #pragma unroll
    for (int o2 = 32; o2 > 0; o2 >>= 1) sq += __shfl_down(sq, o2, 64);
    if (lane == 0) red[4 + wid] = sq;
    __syncthreads();
    float var  = (red[4] + red[5] + red[6] + red[7]) * (1.f / 4096.f);
    float rstd = rsqrtf(var + 1e-5f);

    int b = n >> 3, d = n & 7;
    float4* outp = (float4*)(out + ((size_t)(b * 64 + co) * 8 + d) * HW);
    #pragma unroll
    for (int r = 0; r < 4; r++) {
        float xs[4] = {v[r].x, v[r].y, v[r].z, v[r].w};
        float4 res;
        float* rp = (float*)&res;
        #pragma unroll
        for (int q = 0; q < 4; q++) {
            float xn = (xs[q] - mean) * rstd;
            rp[q] = 0.5f * xn * (1.f + erff(xn * 0.70710678118654752f));
        }
        outp[t + r * 256] = res;
    }
}

// ---------------------------------------------------------------------------
extern "C" void kernel_launch(void* const* d_in, const int* in_sizes, int n_in,
                              void* d_out, int out_size, void* d_ws, size_t ws_size,
                              hipStream_t stream) {
    const float* x     = (const float*)d_in[0];
    const float* w_off = (const float*)d_in[1];
    const float* b_off = (const float*)d_in[2];
    const float* w_dc  = (const float*)d_in[3];
    const float* b_dc  = (const float*)d_in[4];
    float* out = (float*)d_out;

    __hip_bfloat16* xTb  = (__hip_bfloat16*)d_ws;              // 8.4M elems = 16.78 MB
    __hip_bfloat16* offb = xTb + (size_t)NN * 4 * HW * 16;     // 9.4M elems = 18.87 MB
    float* outpre = (float*)(offb + (size_t)NN * 72 * HW);     // 8.4M elems = 33.55 MB

    transpose_x<<<2048, 256, 0, stream>>>(x, (unsigned short*)xTb);
    off_conv   <<<2048, 256, 0, stream>>>(x, w_off, b_off, offb);
    deform_conv<<<1024, 256, 0, stream>>>((const unsigned short*)xTb, offb, w_dc, b_dc, outpre);
    norm_gelu  <<<2048, 256, 0, stream>>>(outpre, out);
}

// Round 4
// 203.655 us; speedup vs baseline: 14.5235x; 1.2378x over previous
//
#include <hip/hip_runtime.h>
#include <hip/hip_bf16.h>
#include <math.h>

#define HW 4096
#define NN 32

__device__ inline unsigned short bfbits(float a) {
    __hip_bfloat16 h = __float2bfloat16(a);
    unsigned short u;
    __builtin_memcpy(&u, &h, 2);
    return u;
}
__device__ inline unsigned packbf(float a, float b) {
    return (unsigned)bfbits(a) | ((unsigned)bfbits(b) << 16);
}
__device__ inline float bflo(unsigned u) { return __uint_as_float(u << 16); }
__device__ inline float bfhi(unsigned u) { return __uint_as_float(u & 0xffff0000u); }
// channel c (0..15) from the two uint4s holding 16 bf16 channels
__device__ inline float chan(const uint4& a, const uint4& b, int c) {
    const unsigned* ua = (const unsigned*)&a;
    const unsigned* ub = (const unsigned*)&b;
    unsigned u = (c < 8) ? ua[c >> 1] : ub[(c - 8) >> 1];
    return (c & 1) ? bfhi(u) : bflo(u);
}

// ---------------------------------------------------------------------------
// Kernel T: x[n][c][pos] (fp32) -> xT[n][g][pos][c16] (bf16, 32B per pos).
// ---------------------------------------------------------------------------
__global__ __launch_bounds__(256) void transpose_x(const float* __restrict__ x,
                                                   unsigned short* __restrict__ xT)
{
    __shared__ float tile[256 * 17];
    int bx = blockIdx.x;
    int n = bx >> 6, g = (bx >> 4) & 3, chunk = bx & 15;
    int t = threadIdx.x;
    const float* xb = x + (size_t)(n * 64 + g * 16) * HW + chunk * 256;

    #pragma unroll
    for (int r = 0; r < 16; r++) {
        int idx = r * 256 + t;
        int c = idx >> 8, p = idx & 255;
        tile[p * 17 + c] = xb[c * HW + p];
    }
    __syncthreads();

    uint4* ob = (uint4*)(xT + ((size_t)(n * 4 + g) * HW + chunk * 256) * 16);
    #pragma unroll
    for (int r = 0; r < 2; r++) {
        int idx = r * 256 + t;
        int p = idx >> 1, half = idx & 1;
        const float* tp = &tile[p * 17 + half * 8];
        uint4 v;
        v.x = packbf(tp[0], tp[1]);
        v.y = packbf(tp[2], tp[3]);
        v.z = packbf(tp[4], tp[5]);
        v.w = packbf(tp[6], tp[7]);
        ob[idx] = v;
    }
}

// ---------------------------------------------------------------------------
// Kernel A2: grouped 3x3 offset conv from bf16 channel-last xT.
// grid 1024 = 32n*4g*8band ; block 256 = 4 rowpairs x 64 cols;
// each thread computes 2 vertically-adjacent positions (weight reads amortized
// 2x; rows padded to 20 floats -> 4xb128+1xb64 LDS reads instead of 18 b32).
// ---------------------------------------------------------------------------
__global__ __launch_bounds__(256) void off_conv2(const unsigned short* __restrict__ xT,
                                                 const float* __restrict__ w_off,
                                                 const float* __restrict__ b_off,
                                                 __hip_bfloat16* __restrict__ off)
{
    __shared__ float wl[9 * 16 * 20];   // [ij][c][d pad 20]
    int bx = blockIdx.x;
    int n = bx >> 5, g = (bx >> 3) & 3, band = bx & 7;
    int t = threadIdx.x;

    for (int idx = t; idx < 2880; idx += 256) {
        int row = idx / 20, d = idx - row * 20;
        int ij = row >> 4, c = row & 15;
        wl[idx] = (d < 18) ? w_off[(g * 18 + d) * 144 + c * 9 + ij] : 0.f;
    }
    __syncthreads();

    int h0 = band * 8 + (t >> 6) * 2;
    int w  = t & 63;
    int pos0 = h0 * 64 + w;
    const uint4* xb = (const uint4*)xT + (size_t)(n * 4 + g) * HW * 2;

    float acc0[18], acc1[18];
    #pragma unroll
    for (int d = 0; d < 18; d++) {
        float b = b_off[g * 18 + d];     // wave-uniform -> scalar loads
        acc0[d] = b; acc1[d] = b;
    }

    #pragma unroll 1
    for (int i = 0; i < 3; i++) {
        #pragma unroll 1
        for (int j = 0; j < 3; j++) {
            int ij = i * 3 + j;
            int r0 = h0 - 1 + i;         // tap row for pos0
            int r1 = r0 + 1;             // tap row for pos1
            int cc = w - 1 + j;
            bool vc = (cc >= 0) && (cc < 64);
            bool v0 = vc && (r0 >= 0) && (r0 < 64);
            bool v1 = vc && (r1 >= 0) && (r1 < 64);
            int i0 = v0 ? (r0 * 64 + cc) : 0;
            int i1 = v1 ? (r1 * 64 + cc) : 0;
            uint4 a0 = xb[i0 * 2], a1 = xb[i0 * 2 + 1];
            uint4 b0 = xb[i1 * 2], b1 = xb[i1 * 2 + 1];
            if (!v0) { a0.x=a0.y=a0.z=a0.w=0u; a1 = a0; }
            if (!v1) { b0.x=b0.y=b0.z=b0.w=0u; b1 = b0; }

            const float* wrow = &wl[ij * 320];
            #pragma unroll
            for (int c = 0; c < 16; c++) {
                float va = chan(a0, a1, c);
                float vb = chan(b0, b1, c);
                const float* wp = &wrow[c * 20];
                float4 w0 = *(const float4*)&wp[0];
                float4 w1 = *(const float4*)&wp[4];
                float4 w2 = *(const float4*)&wp[8];
                float4 w3 = *(const float4*)&wp[12];
                float2 w4 = *(const float2*)&wp[16];
                float wv[18] = {w0.x,w0.y,w0.z,w0.w, w1.x,w1.y,w1.z,w1.w,
                                w2.x,w2.y,w2.z,w2.w, w3.x,w3.y,w3.z,w3.w,
                                w4.x,w4.y};
                #pragma unroll
                for (int d = 0; d < 18; d++) {
                    acc0[d] = fmaf(wv[d], va, acc0[d]);
                    acc1[d] = fmaf(wv[d], vb, acc1[d]);
                }
            }
        }
    }

    __hip_bfloat16* ob = off + (size_t)(n * 72 + g * 18) * HW + pos0;
    #pragma unroll
    for (int d = 0; d < 18; d++) {
        ob[d * HW]      = __float2bfloat16(acc0[d]);
        ob[d * HW + 64] = __float2bfloat16(acc1[d]);
    }
}

// ---------------------------------------------------------------------------
// Kernel B: deformable bilinear gather (bf16 uint4, 2 pos/thread) + 16x16x9.
// ---------------------------------------------------------------------------
__device__ inline void bilin_setup(int h, int w, int ki, int kj, float dy, float dx,
                                   float* ww, int* ss) {
    float py = (float)(h - 1 + ki) + dy;
    float px = (float)(w - 1 + kj) + dx;
    float y0f = floorf(py), x0f = floorf(px);
    float ly = py - y0f, lx = px - x0f;
    int y0 = (int)y0f, x0 = (int)x0f;
    int y1 = y0 + 1, x1 = x0 + 1;
    float vy0 = (y0 >= 0 && y0 < 64) ? 1.f : 0.f;
    float vy1 = (y1 >= 0 && y1 < 64) ? 1.f : 0.f;
    float vx0 = (x0 >= 0 && x0 < 64) ? 1.f : 0.f;
    float vx1 = (x1 >= 0 && x1 < 64) ? 1.f : 0.f;
    ww[0] = (1.f - ly) * (1.f - lx) * vy0 * vx0;
    ww[1] = (1.f - ly) * lx         * vy0 * vx1;
    ww[2] = ly         * (1.f - lx) * vy1 * vx0;
    ww[3] = ly         * lx         * vy1 * vx1;
    int yc0 = min(max(y0, 0), 63) * 64, yc1 = min(max(y1, 0), 63) * 64;
    int xc0 = min(max(x0, 0), 63),      xc1 = min(max(x1, 0), 63);
    ss[0] = yc0 + xc0; ss[1] = yc0 + xc1; ss[2] = yc1 + xc0; ss[3] = yc1 + xc1;
}

__device__ inline void bilin8(uint4 A, uint4 B, uint4 C, uint4 D,
                              const float* ww, float* val) {
    const unsigned* ua = (const unsigned*)&A;
    const unsigned* ub = (const unsigned*)&B;
    const unsigned* uc = (const unsigned*)&C;
    const unsigned* ud = (const unsigned*)&D;
    #pragma unroll
    for (int j = 0; j < 4; j++) {
        val[2*j]   = ww[0]*bflo(ua[j]) + ww[1]*bflo(ub[j]) + ww[2]*bflo(uc[j]) + ww[3]*bflo(ud[j]);
        val[2*j+1] = ww[0]*bfhi(ua[j]) + ww[1]*bfhi(ub[j]) + ww[2]*bfhi(uc[j]) + ww[3]*bfhi(ud[j]);
    }
}

__global__ __launch_bounds__(256) void deform_conv(const unsigned short* __restrict__ xT,
                                                   const __hip_bfloat16* __restrict__ off,
                                                   const float* __restrict__ w_dc,
                                                   const float* __restrict__ b_dc,
                                                   float* __restrict__ outpre)
{
    __shared__ float wl[2304];   // [(c*9+k)*16 + o]
    int bx = blockIdx.x;
    int n = bx >> 5, g = (bx >> 3) & 3, chunk = bx & 7;
    int t = threadIdx.x;

    for (int idx = t; idx < 2304; idx += 256) {
        int ck = idx >> 4, o = idx & 15;
        wl[idx] = w_dc[(g * 16 + o) * 144 + ck];
    }
    __syncthreads();

    int pos0 = chunk * 512 + t;
    int pos1 = pos0 + 256;
    int h0 = pos0 >> 6, w0 = pos0 & 63;
    int h1 = pos1 >> 6, w1 = pos1 & 63;
    const uint4* xb = (const uint4*)xT + (size_t)(n * 4 + g) * HW * 2;
    const __hip_bfloat16* ob = off + (size_t)(n * 72 + g * 18) * HW;

    float acc0[16], acc1[16];
    #pragma unroll
    for (int o = 0; o < 16; o++) { float b = b_dc[g * 16 + o]; acc0[o] = b; acc1[o] = b; }

    #pragma unroll 1
    for (int k = 0; k < 9; k++) {
        int ki = k / 3, kj = k - ki * 3;
        float dy0 = __bfloat162float(ob[(2 * k + 0) * HW + pos0]);
        float dx0 = __bfloat162float(ob[(2 * k + 1) * HW + pos0]);
        float dy1 = __bfloat162float(ob[(2 * k + 0) * HW + pos1]);
        float dx1 = __bfloat162float(ob[(2 * k + 1) * HW + pos1]);
        float ww0[4], ww1[4];
        int ss0[4], ss1[4];
        bilin_setup(h0, w0, ki, kj, dy0, dx0, ww0, ss0);
        bilin_setup(h1, w1, ki, kj, dy1, dx1, ww1, ss1);

        #pragma unroll
        for (int q = 0; q < 2; q++) {
            float val0[8], val1[8];
            bilin8(xb[ss0[0] * 2 + q], xb[ss0[1] * 2 + q],
                   xb[ss0[2] * 2 + q], xb[ss0[3] * 2 + q], ww0, val0);
            bilin8(xb[ss1[0] * 2 + q], xb[ss1[1] * 2 + q],
                   xb[ss1[2] * 2 + q], xb[ss1[3] * 2 + q], ww1, val1);
            #pragma unroll
            for (int c = 0; c < 8; c++) {
                const float4* wp = (const float4*)&wl[((q * 8 + c) * 9 + k) * 16];
                float v0 = val0[c], v1 = val1[c];
                #pragma unroll
                for (int o4 = 0; o4 < 4; o4++) {
                    float4 wv = wp[o4];
                    acc0[o4*4+0] = fmaf(wv.x, v0, acc0[o4*4+0]);
                    acc0[o4*4+1] = fmaf(wv.y, v0, acc0[o4*4+1]);
                    acc0[o4*4+2] = fmaf(wv.z, v0, acc0[o4*4+2]);
                    acc0[o4*4+3] = fmaf(wv.w, v0, acc0[o4*4+3]);
                    acc1[o4*4+0] = fmaf(wv.x, v1, acc1[o4*4+0]);
                    acc1[o4*4+1] = fmaf(wv.y, v1, acc1[o4*4+1]);
                    acc1[o4*4+2] = fmaf(wv.z, v1, acc1[o4*4+2]);
                    acc1[o4*4+3] = fmaf(wv.w, v1, acc1[o4*4+3]);
                }
            }
        }
    }

    float* op = outpre + (size_t)(n * 64 + g * 16) * HW;
    #pragma unroll
    for (int o = 0; o < 16; o++) {
        op[o * HW + pos0] = acc0[o];
        op[o * HW + pos1] = acc1[o];
    }
}

// ---------------------------------------------------------------------------
// Kernel C: per-(n,cout) spatial mean/var + exact GELU + transposed store.
// ---------------------------------------------------------------------------
__global__ __launch_bounds__(256) void norm_gelu(const float* __restrict__ outpre,
                                                 float* __restrict__ out)
{
    __shared__ float red[8];
    int bx = blockIdx.x;
    int n  = bx >> 6;
    int co = bx & 63;
    int t  = threadIdx.x;

    const float4* base = (const float4*)(outpre + (size_t)(n * 64 + co) * HW);
    float4 v[4];
    float s = 0.f;
    #pragma unroll
    for (int r = 0; r < 4; r++) {
        v[r] = base[t + r * 256];
        s += v[r].x + v[r].y + v[r].z + v[r].w;
    }
    #pragma unroll
    for (int o2 = 32; o2 > 0; o2 >>= 1) s += __shfl_down(s, o2, 64);
    int wid = t >> 6, lane = t & 63;
    if (lane == 0) red[wid] = s;
    __syncthreads();
    float mean = (red[0] + red[1] + red[2] + red[3]) * (1.f / 4096.f);

    float sq = 0.f;
    #pragma unroll
    for (int r = 0; r < 4; r++) {
        float a = v[r].x - mean, b = v[r].y - mean;
        float c = v[r].z - mean, d = v[r].w - mean;
        sq += a * a + b * b + c * c + d * d;
    }
    #pragma unroll
    for (int o2 = 32; o2 > 0; o2 >>= 1) sq += __shfl_down(sq, o2, 64);
    if (lane == 0) red[4 + wid] = sq;
    __syncthreads();
    float var  = (red[4] + red[5] + red[6] + red[7]) * (1.f / 4096.f);
    float rstd = rsqrtf(var + 1e-5f);

    int b = n >> 3, d = n & 7;
    float4* outp = (float4*)(out + ((size_t)(b * 64 + co) * 8 + d) * HW);
    #pragma unroll
    for (int r = 0; r < 4; r++) {
        float xs[4] = {v[r].x, v[r].y, v[r].z, v[r].w};
        float4 res;
        float* rp = (float*)&res;
        #pragma unroll
        for (int q = 0; q < 4; q++) {
            float xn = (xs[q] - mean) * rstd;
            rp[q] = 0.5f * xn * (1.f + erff(xn * 0.70710678118654752f));
        }
        outp[t + r * 256] = res;
    }
}

// ---------------------------------------------------------------------------
extern "C" void kernel_launch(void* const* d_in, const int* in_sizes, int n_in,
                              void* d_out, int out_size, void* d_ws, size_t ws_size,
                              hipStream_t stream) {
    const float* x     = (const float*)d_in[0];
    const float* w_off = (const float*)d_in[1];
    const float* b_off = (const float*)d_in[2];
    const float* w_dc  = (const float*)d_in[3];
    const float* b_dc  = (const float*)d_in[4];
    float* out = (float*)d_out;

    __hip_bfloat16* xTb  = (__hip_bfloat16*)d_ws;              // 16.78 MB
    __hip_bfloat16* offb = xTb + (size_t)NN * 4 * HW * 16;     // 18.87 MB
    float* outpre = (float*)(offb + (size_t)NN * 72 * HW);     // 33.55 MB

    transpose_x<<<2048, 256, 0, stream>>>(x, (unsigned short*)xTb);
    off_conv2  <<<1024, 256, 0, stream>>>((const unsigned short*)xTb, w_off, b_off, offb);
    deform_conv<<<1024, 256, 0, stream>>>((const unsigned short*)xTb, offb, w_dc, b_dc, outpre);
    norm_gelu  <<<2048, 256, 0, stream>>>(outpre, out);
}